// Round 1
// baseline (156.720 us; speedup 1.0000x reference)
//
#include <hip/hip_runtime.h>
#include <hip/hip_bf16.h>
#include <math.h>

// LargeMarginLoss: loss = log1p(neg_sum / pos_sum) over e = exp(30*(cos_sim - 0.2))
// B=8192, D=512, labels in [0,100). Output: 1 float32 scalar.

#define BDIM 8192
#define DDIM 512
#define MARGIN 0.2f
#define SCALE 30.0f

#define BM 128
#define BN 128
#define BK 32
#define NTILES (BDIM / BM)   // 64

typedef __hip_bfloat16 bf16;
using f32x4  = __attribute__((ext_vector_type(4))) float;
using bf16x8 = __attribute__((ext_vector_type(8))) short;  // 8 bf16 = 4 VGPRs

#define GLOAD_LDS16(gp, lp)                                                    \
    __builtin_amdgcn_global_load_lds(                                          \
        (const __attribute__((address_space(1))) unsigned int*)(gp),           \
        (__attribute__((address_space(3))) unsigned int*)(lp), 16, 0, 0)

// ---------------------------------------------------------------------------
// Kernel 1: row L2-normalize (fp32 norms, matching jnp), emit bf16 matrix.
// One block (256 threads) per row; each thread handles 2 floats.
__global__ void norm_rows_kernel(const float* __restrict__ emb,
                                 bf16* __restrict__ nout) {
    const int row = blockIdx.x;
    const int t = threadIdx.x;                 // 0..255
    const float2 v = ((const float2*)(emb + (size_t)row * DDIM))[t];
    float ss = v.x * v.x + v.y * v.y;
    #pragma unroll
    for (int off = 32; off > 0; off >>= 1) ss += __shfl_down(ss, off, 64);
    __shared__ float partial[4];
    const int wave = t >> 6, lane = t & 63;
    if (lane == 0) partial[wave] = ss;
    __syncthreads();
    __shared__ float s_inv;
    if (t == 0) {
        float tot = partial[0] + partial[1] + partial[2] + partial[3];
        float nrm = fmaxf(sqrtf(tot), 1e-8f);
        s_inv = 1.0f / nrm;
    }
    __syncthreads();
    const float inv = s_inv;
    __hip_bfloat162 h2;
    h2.x = __float2bfloat16(v.x * inv);
    h2.y = __float2bfloat16(v.y * inv);
    ((__hip_bfloat162*)(nout + (size_t)row * DDIM))[t] = h2;
}

// ---------------------------------------------------------------------------
// Kernel 2: fused sim-GEMM (n @ n^T via bf16 MFMA) + exp + masked reduction.
// 128x128 output tile per block, 4 waves in 2x2, each wave 64x64 (4x4 frags
// of 16x16x32). Upper-triangular blocks only; off-diagonal weighted 2x.
__global__ __launch_bounds__(256)
void gemm_loss_kernel(const bf16* __restrict__ nmat,
                      const int* __restrict__ labels,
                      double* __restrict__ accum /* [0]=pos, [1]=neg */) {
    const int bj = blockIdx.x;   // col tile
    const int bi = blockIdx.y;   // row tile
    if (bj < bi) return;         // symmetry: upper triangle only

    __shared__ short As[BM * BK];   // [row][k], row stride 32 elems (64 B)
    __shared__ short Bs[BN * BK];
    __shared__ int   lr[BM];
    __shared__ int   lc[BN];
    __shared__ double red[8];

    const int t = threadIdx.x;        // 0..255
    const int wave = t >> 6;
    const int lane = t & 63;

    if (t < 128) lr[t] = labels[bi * BM + t];
    else         lc[t - 128] = labels[bj * BN + (t - 128)];

    const int wr = wave >> 1;         // wave row in 2x2
    const int wc = wave & 1;          // wave col

    f32x4 acc[4][4] = {};

    // Staging: per wave, 2 issues each for A and B. Lane l loads 16 B
    // (8 bf16) from global row (i*64 + wave*16 + (l>>2)), col (l&3)*8.
    // LDS dest is wave-uniform base + lane*16 (linear row-major tile).
    const int srow = (lane >> 2);            // 0..15 within wave chunk
    const int scol = (lane & 3) * 8;         // 0,8,16,24
    const bf16* gA0 = nmat + (size_t)(bi * BM + wave * 16 + srow) * DDIM + scol;
    const bf16* gA1 = gA0 + (size_t)64 * DDIM;
    const bf16* gB0 = nmat + (size_t)(bj * BN + wave * 16 + srow) * DDIM + scol;
    const bf16* gB1 = gB0 + (size_t)64 * DDIM;
    short* lA0 = As + (wave * 16) * BK;      // bytes: wave*1024
    short* lA1 = As + (64 + wave * 16) * BK;
    short* lB0 = Bs + (wave * 16) * BK;
    short* lB1 = Bs + (64 + wave * 16) * BK;

    // Fragment read addresses (within LDS tiles)
    const int frow = lane & 15;              // row within 16x16 frag
    const int koff = (lane >> 4) * 8;        // k offset 0/8/16/24

    #pragma unroll 1
    for (int kt = 0; kt < DDIM / BK; ++kt) {
        const int k0 = kt * BK;
        GLOAD_LDS16(gA0 + k0, lA0);
        GLOAD_LDS16(gA1 + k0, lA1);
        GLOAD_LDS16(gB0 + k0, lB0);
        GLOAD_LDS16(gB1 + k0, lB1);
        __syncthreads();   // waits vmcnt(0): staged data visible

        bf16x8 af[4], bfr[4];
        #pragma unroll
        for (int m = 0; m < 4; ++m)
            af[m] = *(const bf16x8*)&As[(wr * 64 + m * 16 + frow) * BK + koff];
        #pragma unroll
        for (int nn = 0; nn < 4; ++nn)
            bfr[nn] = *(const bf16x8*)&Bs[(wc * 64 + nn * 16 + frow) * BK + koff];
        #pragma unroll
        for (int m = 0; m < 4; ++m)
            #pragma unroll
            for (int nn = 0; nn < 4; ++nn)
                acc[m][nn] = __builtin_amdgcn_mfma_f32_16x16x32_bf16(
                    af[m], bfr[nn], acc[m][nn], 0, 0, 0);
        __syncthreads();   // before next iteration overwrites LDS
    }

    // Epilogue: e = exp(SCALE*(sim - MARGIN)); masked accumulate.
    // C/D layout (verified m89): col = lane&15, row = (lane>>4)*4 + reg.
    const float k_scale = SCALE;
    float posf = 0.0f, negf = 0.0f;
    const int rbase = wr * 64 + (lane >> 4) * 4;
    const int cbase = wc * 64 + (lane & 15);
    #pragma unroll
    for (int m = 0; m < 4; ++m) {
        #pragma unroll
        for (int nn = 0; nn < 4; ++nn) {
            const int lcol = cbase + nn * 16;
            const int ljv = lc[lcol];
            #pragma unroll
            for (int r = 0; r < 4; ++r) {
                const int lrow = rbase + m * 16 + r;
                const float sim = acc[m][nn][r];
                const float e = __expf(k_scale * (sim - MARGIN));
                if (lr[lrow] == ljv) posf += e; else negf += e;
            }
        }
    }

    double dp = (double)posf, dn = (double)negf;
    #pragma unroll
    for (int off = 32; off > 0; off >>= 1) {
        dp += __shfl_down(dp, off, 64);
        dn += __shfl_down(dn, off, 64);
    }
    if (lane == 0) { red[wave * 2] = dp; red[wave * 2 + 1] = dn; }
    __syncthreads();
    if (t == 0) {
        const double w = (bi == bj) ? 1.0 : 2.0;
        double p = (red[0] + red[2]) + (red[4] + red[6]);
        double q = (red[1] + red[3]) + (red[5] + red[7]);
        atomicAdd(&accum[0], p * w);
        atomicAdd(&accum[1], q * w);
    }
}

// ---------------------------------------------------------------------------
__global__ void finalize_kernel(const double* __restrict__ accum,
                                float* __restrict__ out) {
    if (threadIdx.x == 0 && blockIdx.x == 0) {
        const double r = accum[1] / accum[0];
        out[0] = (float)log1p(r);
    }
}

// ---------------------------------------------------------------------------
extern "C" void kernel_launch(void* const* d_in, const int* in_sizes, int n_in,
                              void* d_out, int out_size, void* d_ws, size_t ws_size,
                              hipStream_t stream) {
    const float* emb   = (const float*)d_in[0];
    const int* labels  = (const int*)d_in[1];   // int64 in ref; harness gives int32
    float* out         = (float*)d_out;

    double* accum = (double*)d_ws;                       // 2 doubles
    bf16* nmat    = (bf16*)((char*)d_ws + 256);          // 8192*512*2 = 8 MB

    hipMemsetAsync(d_ws, 0, 256, stream);
    norm_rows_kernel<<<BDIM, 256, 0, stream>>>(emb, nmat);
    dim3 grid(NTILES, NTILES);
    gemm_loss_kernel<<<grid, 256, 0, stream>>>(nmat, labels, accum);
    finalize_kernel<<<1, 64, 0, stream>>>(accum, out);
}

// Round 2
// 143.834 us; speedup vs baseline: 1.0896x; 1.0896x over previous
//
#include <hip/hip_runtime.h>
#include <hip/hip_bf16.h>
#include <math.h>

// LargeMarginLoss: loss = log1p(neg_sum / pos_sum) over e = exp(30*(cos_sim - 0.2))
// B=8192, D=512, labels in [0,100). Output: 1 float32 scalar.

#define BDIM 8192
#define DDIM 512
#define MARGIN 0.2f
#define SCALE 30.0f

#define BM 128
#define BN 128
#define BK 32
#define NKT (DDIM / BK)      // 16 K-steps
#define NTILES (BDIM / BM)   // 64
#define NBLK (NTILES * (NTILES + 1) / 2)  // 2080 upper-tri blocks

typedef __hip_bfloat16 bf16;
using f32x4  = __attribute__((ext_vector_type(4))) float;
using bf16x8 = __attribute__((ext_vector_type(8))) short;   // 8 bf16 = 4 VGPRs
using us8    = __attribute__((ext_vector_type(8))) unsigned short;

#define GLOAD_LDS16(gp, lp)                                                    \
    __builtin_amdgcn_global_load_lds(                                          \
        (const __attribute__((address_space(1))) unsigned int*)(gp),           \
        (__attribute__((address_space(3))) unsigned int*)(lp), 16, 0, 0)

__device__ __forceinline__ unsigned short f2bf(float x) {
    union { bf16 h; unsigned short u; } c;
    c.h = __float2bfloat16(x);
    return c.u;
}

// ---------------------------------------------------------------------------
// Kernel 1: row L2-normalize (fp32 norms, matching jnp), emit bf16 matrix.
// One wave per row (4 rows/block); float4 x2 loads, xor-shuffle reduce,
// 16B vector store. No LDS, no __syncthreads.
__global__ __launch_bounds__(256)
void norm_rows_kernel(const float* __restrict__ emb, bf16* __restrict__ nout) {
    const int row  = blockIdx.x * 4 + (threadIdx.x >> 6);
    const int lane = threadIdx.x & 63;
    const float4* src = (const float4*)(emb + (size_t)row * DDIM) + lane * 2;
    const float4 a = src[0];
    const float4 b = src[1];
    float ss = a.x * a.x + a.y * a.y + a.z * a.z + a.w * a.w
             + b.x * b.x + b.y * b.y + b.z * b.z + b.w * b.w;
    #pragma unroll
    for (int off = 1; off < 64; off <<= 1) ss += __shfl_xor(ss, off, 64);
    const float inv = 1.0f / fmaxf(sqrtf(ss), 1e-8f);

    float v[8] = { a.x, a.y, a.z, a.w, b.x, b.y, b.z, b.w };
    us8 o;
    #pragma unroll
    for (int i = 0; i < 8; ++i) o[i] = f2bf(v[i] * inv);
    *((us8*)(nout + (size_t)row * DDIM) + lane) = o;
}

// ---------------------------------------------------------------------------
// Kernel 2: fused sim-GEMM (n @ n^T via bf16 MFMA) + exp + masked reduction.
// 128x128 tile per block, 4 waves (2x2), each wave 4x4 frags of 16x16x32.
// Upper-triangular blocks only (triangular grid); off-diag weighted 2x.
// 2-deep LDS double-buffer pipeline: raw s_barrier + counted vmcnt(4).
__global__ __launch_bounds__(256, 4)
void gemm_loss_kernel(const bf16* __restrict__ nmat,
                      const int* __restrict__ labels,
                      double* __restrict__ accum /* [0]=pos, [1]=neg */) {
    // --- triangular block decode: l -> (bi, bj), bi <= bj ---
    const int l = blockIdx.x;
    auto off = [](int b) { return (129 * b - b * b) >> 1; };  // row-start index
    int bi = (int)((129.0 - sqrt(16641.0 - 8.0 * (double)l)) * 0.5);
    if (bi < 0) bi = 0;
    if (bi > 63) bi = 63;
    while (bi > 0 && off(bi) > l) --bi;
    while (off(bi + 1) <= l) ++bi;
    const int bj = bi + (l - off(bi));

    __shared__ alignas(16) short As[2][BM * BK];  // [buf][row][k], 8KB each
    __shared__ alignas(16) short Bs[2][BN * BK];
    __shared__ int    lr[BM];
    __shared__ int    lc[BN];
    __shared__ double red[8];

    const int t = threadIdx.x;        // 0..255
    const int wave = t >> 6;
    const int lane = t & 63;

    if (t < 128) lr[t] = labels[bi * BM + t];
    else         lc[t - 128] = labels[bj * BN + (t - 128)];

    const int wr = wave >> 1;         // wave row in 2x2
    const int wc = wave & 1;          // wave col

    f32x4 acc[4][4] = {};

    // Staging addresses: lane l loads 16B from global row (wave*16 + (l>>2)),
    // col (l&3)*8. LDS dest = wave-uniform base + lane*16 (linear row-major).
    const int srow = (lane >> 2);
    const int scol = (lane & 3) * 8;
    const bf16* gA0 = nmat + (size_t)(bi * BM + wave * 16 + srow) * DDIM + scol;
    const bf16* gA1 = gA0 + (size_t)64 * DDIM;
    const bf16* gB0 = nmat + (size_t)(bj * BN + wave * 16 + srow) * DDIM + scol;
    const bf16* gB1 = gB0 + (size_t)64 * DDIM;

    const int frow = lane & 15;       // row within 16x16 frag
    const int koff = (lane >> 4) * 8; // k offset 0/8/16/24

    auto STAGE = [&](int buf, int kt) {
        const int k0 = kt * BK;
        GLOAD_LDS16(gA0 + k0, &As[buf][(wave * 16) * BK]);
        GLOAD_LDS16(gA1 + k0, &As[buf][(64 + wave * 16) * BK]);
        GLOAD_LDS16(gB0 + k0, &Bs[buf][(wave * 16) * BK]);
        GLOAD_LDS16(gB1 + k0, &Bs[buf][(64 + wave * 16) * BK]);
    };
    auto COMPUTE = [&](int buf) {
        bf16x8 af[4], bfr[4];
        #pragma unroll
        for (int m = 0; m < 4; ++m)
            af[m] = *(const bf16x8*)&As[buf][(wr * 64 + m * 16 + frow) * BK + koff];
        #pragma unroll
        for (int n = 0; n < 4; ++n)
            bfr[n] = *(const bf16x8*)&Bs[buf][(wc * 64 + n * 16 + frow) * BK + koff];
        #pragma unroll
        for (int m = 0; m < 4; ++m)
            #pragma unroll
            for (int n = 0; n < 4; ++n)
                acc[m][n] = __builtin_amdgcn_mfma_f32_16x16x32_bf16(
                    af[m], bfr[n], acc[m][n], 0, 0, 0);
    };

    // --- 2-deep pipeline: buffers kt and kt+1 always in flight ---
    STAGE(0, 0);
    STAGE(1, 1);                      // 8 outstanding loads per wave
    #pragma unroll 2
    for (int kt = 0; kt < NKT - 2; ++kt) {
        // wait for current buffer's 4 loads; next buffer's 4 stay in flight
        asm volatile("s_waitcnt vmcnt(4)" ::: "memory");
        __builtin_amdgcn_s_barrier();          // all waves: current buf ready
        asm volatile("" ::: "memory");
        COMPUTE(kt & 1);
        asm volatile("" ::: "memory");
        __builtin_amdgcn_s_barrier();          // all waves done reading buf
        asm volatile("" ::: "memory");
        STAGE(kt & 1, kt + 2);                 // refill freed buffer
    }
    // kt = NKT-2: current buf 0 ready after vmcnt(4); no more staging
    asm volatile("s_waitcnt vmcnt(4)" ::: "memory");
    __builtin_amdgcn_s_barrier();
    asm volatile("" ::: "memory");
    COMPUTE((NKT - 2) & 1);
    // kt = NKT-1: drain remaining 4 loads (buf 1)
    asm volatile("s_waitcnt vmcnt(0)" ::: "memory");
    __builtin_amdgcn_s_barrier();
    asm volatile("" ::: "memory");
    COMPUTE((NKT - 1) & 1);

    // --- epilogue: e = exp(SCALE*(sim - MARGIN)); masked accumulate ---
    // C/D layout: col = lane&15, row = (lane>>4)*4 + reg.
    float posf = 0.0f, negf = 0.0f;
    const int rbase = wr * 64 + (lane >> 4) * 4;
    const int cbase = wc * 64 + (lane & 15);
    #pragma unroll
    for (int m = 0; m < 4; ++m) {
        #pragma unroll
        for (int nn = 0; nn < 4; ++nn) {
            const int ljv = lc[cbase + nn * 16];
            #pragma unroll
            for (int r = 0; r < 4; ++r) {
                const float sim = acc[m][nn][r];
                const float e = __expf(fmaf(sim, SCALE, -SCALE * MARGIN));
                if (lr[rbase + m * 16 + r] == ljv) posf += e; else negf += e;
            }
        }
    }

    double dp = (double)posf, dn = (double)negf;
    #pragma unroll
    for (int o = 32; o > 0; o >>= 1) {
        dp += __shfl_down(dp, o, 64);
        dn += __shfl_down(dn, o, 64);
    }
    if (lane == 0) { red[wave * 2] = dp; red[wave * 2 + 1] = dn; }
    __syncthreads();
    if (t == 0) {
        const double w = (bi == bj) ? 1.0 : 2.0;
        double p = (red[0] + red[2]) + (red[4] + red[6]);
        double q = (red[1] + red[3]) + (red[5] + red[7]);
        atomicAdd(&accum[0], p * w);
        atomicAdd(&accum[1], q * w);
    }
}

// ---------------------------------------------------------------------------
__global__ void finalize_kernel(const double* __restrict__ accum,
                                float* __restrict__ out) {
    if (threadIdx.x == 0 && blockIdx.x == 0) {
        const double r = accum[1] / accum[0];
        out[0] = (float)log1p(r);
    }
}

// ---------------------------------------------------------------------------
extern "C" void kernel_launch(void* const* d_in, const int* in_sizes, int n_in,
                              void* d_out, int out_size, void* d_ws, size_t ws_size,
                              hipStream_t stream) {
    const float* emb   = (const float*)d_in[0];
    const int* labels  = (const int*)d_in[1];
    float* out         = (float*)d_out;

    double* accum = (double*)d_ws;                       // 2 doubles
    bf16* nmat    = (bf16*)((char*)d_ws + 256);          // 8192*512*2 = 8 MB

    hipMemsetAsync(d_ws, 0, 256, stream);
    norm_rows_kernel<<<BDIM / 4, 256, 0, stream>>>(emb, nmat);
    gemm_loss_kernel<<<NBLK, 256, 0, stream>>>(nmat, labels, accum);
    finalize_kernel<<<1, 64, 0, stream>>>(accum, out);
}

// Round 6
// 134.481 us; speedup vs baseline: 1.1654x; 1.0695x over previous
//
#include <hip/hip_runtime.h>
#include <hip/hip_bf16.h>
#include <math.h>

// LargeMarginLoss: loss = log1p(neg_sum / pos_sum) over e = exp(30*(cos_sim - 0.2))
// B=8192, D=512, labels in [0,100). Output: 1 float32 scalar.
//
// Structure: norm (fp32 norms -> bf16 rows) ; fused 256^2 8-phase MFMA GEMM
// (n @ n^T, triangular grid, exp+mask+reduce epilogue, last-block finalize).

#define BDIM 8192
#define DDIM 512
#define MARGIN 0.2f
#define SCALE 30.0f

#define BT 256               // output tile (BM=BN)
#define BK 64                // K-step
#define NKT (DDIM / BK)      // 8 K-tiles
#define NT (BDIM / BT)       // 32
#define NBLK (NT * (NT + 1) / 2)   // 528 upper-tri tiles

typedef __hip_bfloat16 bf16;
using f32x4  = __attribute__((ext_vector_type(4))) float;
using bf16x8 = __attribute__((ext_vector_type(8))) short;
using us8    = __attribute__((ext_vector_type(8))) unsigned short;

#define GLOAD_LDS16(gp, lp)                                                    \
    __builtin_amdgcn_global_load_lds(                                          \
        (const __attribute__((address_space(1))) unsigned int*)(gp),           \
        (__attribute__((address_space(3))) unsigned int*)(lp), 16, 0, 0)

__device__ __forceinline__ unsigned short f2bf(float x) {
    union { bf16 h; unsigned short u; } c;
    c.h = __float2bfloat16(x);
    return c.u;
}

// ---------------------------------------------------------------------------
// Kernel 1: row L2-normalize, emit bf16. One wave per row; block 0 thread 0
// zero-inits the accumulators + completion counter (replaces memset node).
__global__ __launch_bounds__(256)
void norm_rows_kernel(const float* __restrict__ emb, bf16* __restrict__ nout,
                      double* __restrict__ accum, unsigned* __restrict__ ctr) {
    if (blockIdx.x == 0 && threadIdx.x == 0) {
        accum[0] = 0.0; accum[1] = 0.0; *ctr = 0u;
    }
    const int row  = blockIdx.x * 4 + (threadIdx.x >> 6);
    const int lane = threadIdx.x & 63;
    const float4* src = (const float4*)(emb + (size_t)row * DDIM) + lane * 2;
    const float4 a = src[0];
    const float4 b = src[1];
    float ss = a.x * a.x + a.y * a.y + a.z * a.z + a.w * a.w
             + b.x * b.x + b.y * b.y + b.z * b.z + b.w * b.w;
    #pragma unroll
    for (int off = 1; off < 64; off <<= 1) ss += __shfl_xor(ss, off, 64);
    const float inv = 1.0f / fmaxf(sqrtf(ss), 1e-8f);
    float v[8] = { a.x, a.y, a.z, a.w, b.x, b.y, b.z, b.w };
    us8 o;
    #pragma unroll
    for (int i = 0; i < 8; ++i) o[i] = f2bf(v[i] * inv);
    *((us8*)(nout + (size_t)row * DDIM) + lane) = o;
}

// ---------------------------------------------------------------------------
// Kernel 2: 256^2-tile 8-phase fused GEMM-loss.
//   8 waves (2M x 4N), per-wave 128x64 output = 8x4 frags of 16x16x32.
//   LDS: A/B tiles [256][64] bf16, double-buffered (128 KB), XOR-swizzled:
//   chunk16' = chunk16 ^ (row&7) (row = 128 B = 8 chunks). gload_lds writes
//   linearly -> swizzle applied on the GLOBAL source column; ds_read applies
//   the same XOR. Counted vmcnt(2): the next K-tile's 3 later stage-units
//   stay in flight across the barrier (drain only at tail).
__global__ __launch_bounds__(512, 2)
void gemm_loss_kernel(const bf16* __restrict__ nmat,
                      const int* __restrict__ labels,
                      double* __restrict__ accum, unsigned* __restrict__ ctr,
                      float* __restrict__ out) {
    // --- triangular decode: l -> (bi, bj), bi <= bj ---
    const int l = blockIdx.x;
    auto tri = [](int b) { return ((65 - b) * b) >> 1; };
    int bi = (int)((65.0 - sqrt(4225.0 - 8.0 * (double)l)) * 0.5);
    bi = bi < 0 ? 0 : (bi > 31 ? 31 : bi);
    while (bi > 0 && tri(bi) > l) --bi;
    while (tri(bi + 1) <= l) ++bi;
    const int bj = bi + (l - tri(bi));

    __shared__ short As[2][BT * BK];   // 32 KB each buf
    __shared__ short Bs[2][BT * BK];
    __shared__ int lr[BT], lc[BT];
    __shared__ double red[16];

    const int t = threadIdx.x, wid = t >> 6, lane = t & 63;
    if (t < 256) lr[t] = labels[bi * BT + t];
    else         lc[t - 256] = labels[bj * BT + (t - 256)];

    const int wm = wid >> 2;          // 0..1  (M half)
    const int wn = wid & 3;           // 0..3  (N quarter)

    // --- staging addresses ---
    // Stage unit = one operand-half (128 rows x 64 cols = 16 KB) = 2 issues
    // per thread. Thread (wid,lane), issue q: LDS shorts offset
    // h*8192 + wid*1024 + q*512 (+ lane*8 by HW); global row
    // tile0 + h*128 + wid*16 + q*8 + (lane>>3); global col chunk pre-swizzled.
    const int srow = wid * 16 + (lane >> 3);
    const int swz8 = ((lane & 7) ^ (lane >> 3)) * 8;  // pre-swizzled col (elems)
    const bf16* gA = nmat + (size_t)(bi * BT + srow) * DDIM + swz8;
    const bf16* gB = nmat + (size_t)(bj * BT + srow) * DDIM + swz8;
    const int ldsw = wid * 1024;

    #define STAGE_A(buf, kt, h)                                                 \
        do {                                                                    \
            GLOAD_LDS16(gA + (size_t)(h) * 128 * DDIM + (kt) * BK,              \
                        &As[buf][(h) * 8192 + ldsw]);                           \
            GLOAD_LDS16(gA + (size_t)(h) * 128 * DDIM + 8 * DDIM + (kt) * BK,   \
                        &As[buf][(h) * 8192 + ldsw + 512]);                     \
        } while (0)
    #define STAGE_B(buf, kt, h)                                                 \
        do {                                                                    \
            GLOAD_LDS16(gB + (size_t)(h) * 128 * DDIM + (kt) * BK,              \
                        &Bs[buf][(h) * 8192 + ldsw]);                           \
            GLOAD_LDS16(gB + (size_t)(h) * 128 * DDIM + 8 * DDIM + (kt) * BK,   \
                        &Bs[buf][(h) * 8192 + ldsw + 512]);                     \
        } while (0)

    // --- fragment read addresses (swizzled) ---
    // A row = wm*128 + m*16 + (lane&15); chunk c = (lane>>4) + kk*4;
    // physical chunk = c ^ (row&7) = c ^ (lane&7).  (shorts)
    const int arow = (wm * 128 + (lane & 15)) * BK;
    const int brow = (wn * 64 + (lane & 15)) * BK;
    const int chk0 = (((lane >> 4) + 0) ^ (lane & 7)) * 8;
    const int chk1 = (((lane >> 4) + 4) ^ (lane & 7)) * 8;

    f32x4 acc[8][4] = {};

    // prologue: stage K-tile 0 into buf 0 (8 loads/thread)
    STAGE_A(0, 0, 0); STAGE_A(0, 0, 1); STAGE_B(0, 0, 0); STAGE_B(0, 0, 1);

    #pragma unroll 2
    for (int kt = 0; kt < NKT; ++kt) {
        const int cur = kt & 1, nxt = cur ^ 1;
        const bool more = (kt + 1 < NKT);
        // stage unit 0 of next K-tile BEFORE the wait -> stays in flight
        if (more) {
            STAGE_A(nxt, kt + 1, 0);
            asm volatile("s_waitcnt vmcnt(2)" ::: "memory");
        } else {
            asm volatile("s_waitcnt vmcnt(0)" ::: "memory");
        }
        __builtin_amdgcn_s_barrier();          // buf[cur] landed for all waves
        asm volatile("" ::: "memory");

        bf16x8 a[4], b[4], a2[4];
        // --- P1: frags m0-3 + B, kk0; stage unit 1 ---
        #pragma unroll
        for (int m = 0; m < 4; ++m)
            a[m] = *(const bf16x8*)&As[cur][arow + m * 1024 + chk0];
        #pragma unroll
        for (int n = 0; n < 4; ++n)
            b[n] = *(const bf16x8*)&Bs[cur][brow + n * 1024 + chk0];
        if (more) STAGE_A(nxt, kt + 1, 1);
        __builtin_amdgcn_s_setprio(1);
        #pragma unroll
        for (int m = 0; m < 4; ++m)
            #pragma unroll
            for (int n = 0; n < 4; ++n)
                acc[m][n] = __builtin_amdgcn_mfma_f32_16x16x32_bf16(
                    a[m], b[n], acc[m][n], 0, 0, 0);
        __builtin_amdgcn_s_setprio(0);
        // --- P2: frags m4-7, kk0; stage unit 2 ---
        #pragma unroll
        for (int m = 0; m < 4; ++m)
            a2[m] = *(const bf16x8*)&As[cur][arow + (m + 4) * 1024 + chk0];
        if (more) STAGE_B(nxt, kt + 1, 0);
        __builtin_amdgcn_s_setprio(1);
        #pragma unroll
        for (int m = 0; m < 4; ++m)
            #pragma unroll
            for (int n = 0; n < 4; ++n)
                acc[m + 4][n] = __builtin_amdgcn_mfma_f32_16x16x32_bf16(
                    a2[m], b[n], acc[m + 4][n], 0, 0, 0);
        __builtin_amdgcn_s_setprio(0);
        // --- P3: frags m0-3 + B, kk1; stage unit 3 ---
        #pragma unroll
        for (int m = 0; m < 4; ++m)
            a[m] = *(const bf16x8*)&As[cur][arow + m * 1024 + chk1];
        #pragma unroll
        for (int n = 0; n < 4; ++n)
            b[n] = *(const bf16x8*)&Bs[cur][brow + n * 1024 + chk1];
        if (more) STAGE_B(nxt, kt + 1, 1);
        __builtin_amdgcn_s_setprio(1);
        #pragma unroll
        for (int m = 0; m < 4; ++m)
            #pragma unroll
            for (int n = 0; n < 4; ++n)
                acc[m][n] = __builtin_amdgcn_mfma_f32_16x16x32_bf16(
                    a[m], b[n], acc[m][n], 0, 0, 0);
        __builtin_amdgcn_s_setprio(0);
        // --- P4: frags m4-7, kk1; release buf[cur] then MFMA ---
        #pragma unroll
        for (int m = 0; m < 4; ++m)
            a2[m] = *(const bf16x8*)&As[cur][arow + (m + 4) * 1024 + chk1];
        asm volatile("s_waitcnt lgkmcnt(0)" ::: "memory");  // my reads done
        __builtin_amdgcn_sched_barrier(0);
        __builtin_amdgcn_s_barrier();          // all waves done with buf[cur]
        asm volatile("" ::: "memory");
        __builtin_amdgcn_s_setprio(1);
        #pragma unroll
        for (int m = 0; m < 4; ++m)
            #pragma unroll
            for (int n = 0; n < 4; ++n)
                acc[m + 4][n] = __builtin_amdgcn_mfma_f32_16x16x32_bf16(
                    a2[m], b[n], acc[m + 4][n], 0, 0, 0);
        __builtin_amdgcn_s_setprio(0);
    }
    #undef STAGE_A
    #undef STAGE_B

    // --- epilogue: e = exp(SCALE*(sim - MARGIN)); masked accumulate ---
    // C/D layout: col = lane&15, row = (lane>>4)*4 + reg.
    float posf = 0.0f, negf = 0.0f;
    const int rbase = wm * 128 + (lane >> 4) * 4;
    const int cbase = wn * 64 + (lane & 15);
    #pragma unroll
    for (int m = 0; m < 8; ++m) {
        #pragma unroll
        for (int n = 0; n < 4; ++n) {
            const int ljv = lc[cbase + n * 16];
            #pragma unroll
            for (int r = 0; r < 4; ++r) {
                const float e = __expf(fmaf(acc[m][n][r], SCALE, -SCALE * MARGIN));
                if (lr[rbase + m * 16 + r] == ljv) posf += e; else negf += e;
            }
        }
    }

    double dp = (double)posf, dn = (double)negf;
    #pragma unroll
    for (int o = 32; o > 0; o >>= 1) {
        dp += __shfl_down(dp, o, 64);
        dn += __shfl_down(dn, o, 64);
    }
    if (lane == 0) { red[wid * 2] = dp; red[wid * 2 + 1] = dn; }
    __syncthreads();
    if (t == 0) {
        const double w = (bi == bj) ? 1.0 : 2.0;
        double p = 0.0, q = 0.0;
        #pragma unroll
        for (int i = 0; i < 8; ++i) { p += red[2 * i]; q += red[2 * i + 1]; }
        atomicAdd(&accum[0], p * w);
        atomicAdd(&accum[1], q * w);
        // last block finalizes (device-scope atomics + fences)
        __threadfence();
        unsigned prev = atomicAdd(ctr, 1u);
        if (prev == NBLK - 1) {
            __threadfence();
            double pp = atomicAdd(&accum[0], 0.0);
            double qq = atomicAdd(&accum[1], 0.0);
            out[0] = (float)log1p(qq / pp);
        }
    }
}

// ---------------------------------------------------------------------------
extern "C" void kernel_launch(void* const* d_in, const int* in_sizes, int n_in,
                              void* d_out, int out_size, void* d_ws, size_t ws_size,
                              hipStream_t stream) {
    const float* emb  = (const float*)d_in[0];
    const int* labels = (const int*)d_in[1];
    float* out        = (float*)d_out;

    double* accum = (double*)d_ws;                       // 2 doubles
    unsigned* ctr = (unsigned*)((char*)d_ws + 16);
    bf16* nmat    = (bf16*)((char*)d_ws + 256);          // 8 MB

    norm_rows_kernel<<<BDIM / 4, 256, 0, stream>>>(emb, nmat, accum, ctr);
    gemm_loss_kernel<<<NBLK, 512, 0, stream>>>(nmat, labels, accum, ctr, out);
}